// Round 1
// baseline (273.400 us; speedup 1.0000x reference)
//
#include <hip/hip_runtime.h>

// RelativeSAMAttention: B=4,H=8,N=1024,DH=128. Outputs FP32: out[B,H,N,DH] ++ scores[B,H,N,N].
//
// R5: SINGLE-PASS. Kill the pass-2 recompute (QK^T + distmap twice) by caching raw
// pre-normalization scores as bf16 in registers:
//   - 32-row blocks (1024 blocks x 512 thr, 8 waves = 2 row-halves x 4 col-quarters):
//     val cache = 32*1024/512 = 64 bf16 = 32 VGPRs -> stays under 128 VGPR (2 blocks/CU).
//   - pass 1: stage K tile ONCE, QK^T + distmap -> val (fp32 rowsum, bf16 cached via cvt_pk).
//   - replay: unpack cache, scores = bf16(val)*inv (fp32 store), sP strip <- cached bf16
//     (no re-conversion), PV on RAW val; O scaled by inv[row] in epilogue (row-uniform).
//   - SCALE folded into Q->bf16; q-geometry pre-scaled by -2 (dist = add + 3 fma).
//   - XCD-aware mapping: bid&7 = xcd owns 4 bh -> per-XCD stage set 2 MB fits L2.

typedef __attribute__((ext_vector_type(8))) short short8;
typedef __attribute__((ext_vector_type(4))) float f32x4;

#define OUT_ELEMS 4194304ull
#define WS_K      0ull           //  8388608 B bf16 K [bh][m][dh]
#define WS_VT     8388608ull     //  8388608 B bf16 V^T [bh][dh][m]
#define WS_CS     16777216ull    //      128 B fp32 cs[32]

__device__ __forceinline__ unsigned short f2bf(float f) {
    unsigned u = __builtin_bit_cast(unsigned, f);
    u += 0x7FFFu + ((u >> 16) & 1u);
    return (unsigned short)(u >> 16);
}
__device__ __forceinline__ float softplus(float x) {
    return fmaxf(x, 0.f) + __logf(1.f + __expf(-fabsf(x)));
}
__device__ __forceinline__ unsigned cvt_pk_bf16(float lo, float hi) {
    unsigned r;
    asm("v_cvt_pk_bf16_f32 %0, %1, %2" : "=v"(r) : "v"(lo), "v"(hi));
    return r;
}

// ---------------- merged prep: blocks [0,512) K-convert, [512,1024) V-transpose, [1024,1056) cs ----
__global__ __launch_bounds__(256) void prep_all(
    const float* __restrict__ k, const float* __restrict__ v, const float* __restrict__ c,
    unsigned short* __restrict__ wsK, unsigned short* __restrict__ wsVt, float* __restrict__ wsCs)
{
    __shared__ unsigned short sT[64 * 132];
    const int blk = blockIdx.x, tid = threadIdx.x;
    if (blk < 512) {
        int t = blk * 256 + tid;
        for (int u = t; u < 524288; u += 131072) {
            float4 a = reinterpret_cast<const float4*>(k)[u * 2];
            float4 b = reinterpret_cast<const float4*>(k)[u * 2 + 1];
            short8 o;
            o[0]=(short)f2bf(a.x); o[1]=(short)f2bf(a.y); o[2]=(short)f2bf(a.z); o[3]=(short)f2bf(a.w);
            o[4]=(short)f2bf(b.x); o[5]=(short)f2bf(b.y); o[6]=(short)f2bf(b.z); o[7]=(short)f2bf(b.w);
            reinterpret_cast<short8*>(wsK)[u] = o;
        }
    } else if (blk < 1024) {
        const int vb = blk - 512;
        const int bh = vb >> 4, m0 = (vb & 15) * 64;
        const float* src = v + ((size_t)bh * 1024 + m0) * 128;
        for (int i = tid; i < 2048; i += 256) {
            int row = i >> 5, c4 = i & 31;
            float4 t = reinterpret_cast<const float4*>(src)[i];
            unsigned long long pk = (unsigned long long)f2bf(t.x)
                                  | ((unsigned long long)f2bf(t.y) << 16)
                                  | ((unsigned long long)f2bf(t.z) << 32)
                                  | ((unsigned long long)f2bf(t.w) << 48);
            *reinterpret_cast<unsigned long long*>(&sT[row * 132 + c4 * 4]) = pk;
        }
        __syncthreads();
        for (int u = tid; u < 2048; u += 256) {
            int dh = u >> 4, ms = u & 15;
            unsigned long long pk = (unsigned long long)sT[(ms*4+0)*132 + dh]
                                  | ((unsigned long long)sT[(ms*4+1)*132 + dh] << 16)
                                  | ((unsigned long long)sT[(ms*4+2)*132 + dh] << 32)
                                  | ((unsigned long long)sT[(ms*4+3)*132 + dh] << 48);
            *reinterpret_cast<unsigned long long*>(&wsVt[((size_t)bh * 128 + dh) * 1024 + m0 + ms * 4]) = pk;
        }
    } else {
        __shared__ float red[4];
        const int bh = blk - 1024;
        float p = 0.f;
        for (int i = tid; i < 1024; i += 256) p += softplus(c[(size_t)bh * 1024 + i]);
        p += __shfl_xor(p, 32, 64); p += __shfl_xor(p, 16, 64); p += __shfl_xor(p, 8, 64);
        p += __shfl_xor(p,  4, 64); p += __shfl_xor(p,  2, 64); p += __shfl_xor(p, 1, 64);
        if ((tid & 63) == 0) red[tid >> 6] = p;
        __syncthreads();
        if (tid == 0) wsCs[bh] = red[0] + red[1] + red[2] + red[3] + 1e-9f;
    }
}

// ---------------- main: single pass with register-cached bf16 raw scores ----------------
__global__ __launch_bounds__(512, 4) void sam_main(
    const float* __restrict__ q, const float* __restrict__ dqp, const float* __restrict__ dkp,
    const float* __restrict__ w_w, const float* __restrict__ b_w,
    const float* __restrict__ w_b, const float* __restrict__ b_b,
    const unsigned short* __restrict__ wsK, const unsigned short* __restrict__ wsVt,
    const float* __restrict__ wsCs, float* __restrict__ out)
{
    __shared__ __align__(16) unsigned short sK[64 * 136];   // K tile [64 m][136]
    __shared__ __align__(16) unsigned short sVt[128 * 72];  // V^T tile [128 dh][72]; front 32*136 doubles as sQ
    __shared__ __align__(16) unsigned short sP[32 * 72];    // raw-score strip [32 n][72]
    __shared__ float sdk[4 * 64];
    __shared__ float s_red[4 * 32];
    __shared__ float s_inv[32];

    const int bid  = blockIdx.x;
    const int xcd  = bid & 7;                 // round-robin XCD assumption (perf-only)
    const int j    = bid >> 3;                // 0..127 within XCD
    const int bh   = xcd * 4 + (j & 3);       // 4 bh per XCD -> 2 MB stage set fits L2
    const int n0   = (j >> 2) * 32;           // 32 row-blocks per bh
    const int b    = bh >> 3;
    const int h    = bh & 7;
    const int tid  = threadIdx.x;
    const int lane = tid & 63;
    const int wave = tid >> 6;
    const int l15  = lane & 15;
    const int quad = lane >> 4;
    const int wr   = wave >> 2;               // row half (16 rows)
    const int wc   = wave & 3;                // col quarter (16 m) / dh quarter (32 dh)
    const int mq   = wc * 16 + l15;           // m-local column this lane owns

    const float ww = w_w[h], bw = b_w[h], wb = w_b[h], bb = b_b[h];
    const float wwn = -ww, bwn = -bw;
    const float SCALE = 0.08838834764831845f;   // 1/sqrt(128), folded into Q

    // ---- prologue: Q rows [n0,n0+32) -> bf16 (pre-scaled) into sQ; dq geometry; cs ----
    unsigned short* sQ = sVt;                 // 32*136 = 4352 shorts <= 9216
    {
        const float* qbase = q + ((size_t)bh * 1024 + n0) * 128;
        for (int i = tid; i < 1024; i += 512) {
            int row = i >> 5, c4 = i & 31;
            float4 t = reinterpret_cast<const float4*>(qbase)[i];
            unsigned long long pk = (unsigned long long)f2bf(t.x * SCALE)
                                  | ((unsigned long long)f2bf(t.y * SCALE) << 16)
                                  | ((unsigned long long)f2bf(t.z * SCALE) << 32)
                                  | ((unsigned long long)f2bf(t.w * SCALE) << 48);
            *reinterpret_cast<unsigned long long*>(&sQ[row * 136 + c4 * 4]) = pk;
        }
    }
    float qxm[4], qym[4], qzm[4], qs[4];
    #pragma unroll
    for (int r = 0; r < 4; r++) {
        int nl = wr * 16 + quad * 4 + r;
        float4 d4 = reinterpret_cast<const float4*>(dqp)[(size_t)b * 1024 + n0 + nl];
        qxm[r] = -2.f * d4.x; qym[r] = -2.f * d4.y; qzm[r] = -2.f * d4.z;
        qs[r] = d4.x*d4.x + d4.y*d4.y + d4.z*d4.z;
    }
    const float cs = wsCs[bh];
    __syncthreads();
    short8 afr[4];
    {
        const unsigned short* aq = &sQ[(wr * 16 + l15) * 136];
        #pragma unroll
        for (int ks = 0; ks < 4; ks++)
            afr[ks] = *reinterpret_cast<const short8*>(aq + ks * 32 + quad * 8);
    }
    __syncthreads();   // sQ region free (becomes sVt in replay)

    // ================= PASS: QK^T + distmap once; cache raw vals =================
    float rs[4] = {0.f, 0.f, 0.f, 0.f};
    unsigned vreg[16][2];                     // 16 tiles x 4 vals packed bf16 = 32 VGPRs
    #pragma unroll
    for (int t = 0; t < 16; t++) {
        const int m0 = t * 64;
        #pragma unroll
        for (int i = 0; i < 2; i++) {         // sK: 64 rows x 16 short8, staged ONCE
            int u = tid + i * 512;
            int row = u >> 4, seg = u & 15;
            short8 d = *reinterpret_cast<const short8*>(wsK + ((size_t)bh * 1024 + m0 + row) * 128 + seg * 8);
            *reinterpret_cast<short8*>(&sK[row * 136 + seg * 8]) = d;
        }
        if (tid < 64) {
            float4 d4 = reinterpret_cast<const float4*>(dkp)[(size_t)b * 1024 + m0 + tid];
            sdk[tid] = d4.x; sdk[64 + tid] = d4.y; sdk[128 + tid] = d4.z;
            sdk[192 + tid] = d4.x*d4.x + d4.y*d4.y + d4.z*d4.z;
        }
        __syncthreads();

        f32x4 cacc = {0.f, 0.f, 0.f, 0.f};
        {
            const unsigned short* bq = &sK[(wc * 16 + l15) * 136];
            #pragma unroll
            for (int ks = 0; ks < 4; ks++) {
                short8 bfr = *reinterpret_cast<const short8*>(bq + ks * 32 + quad * 8);
                cacc = __builtin_amdgcn_mfma_f32_16x16x32_bf16(afr[ks], bfr, cacc, 0, 0, 0);
            }
        }
        const float kx = sdk[mq], ky = sdk[64 + mq], kz = sdk[128 + mq], ksq = sdk[192 + mq];
        float val[4];
        #pragma unroll
        for (int r = 0; r < 4; r++) {
            float dist = qs[r] + ksq + qxm[r]*kx + qym[r]*ky + qzm[r]*kz;   // add + 3 fma
            float aw = softplus(dist * wwn + bwn);
            float ab = dist * wb + bb;
            val[r] = fmaxf(cacc[r] * aw + ab, 0.f);     // cacc pre-scaled via Q
            rs[r] += val[r];
        }
        vreg[t][0] = cvt_pk_bf16(val[0], val[1]);
        vreg[t][1] = cvt_pk_bf16(val[2], val[3]);
        __syncthreads();   // sK/sdk reads done before next restage
    }

    // ---- rowsums -> invd (block-local; each block owns its 32 rows) ----
    #pragma unroll
    for (int r = 0; r < 4; r++) {
        float tsum = rs[r];
        tsum += __shfl_xor(tsum, 1, 64);
        tsum += __shfl_xor(tsum, 2, 64);
        tsum += __shfl_xor(tsum, 4, 64);
        tsum += __shfl_xor(tsum, 8, 64);
        if (l15 == 0) s_red[wc * 32 + wr * 16 + quad * 4 + r] = tsum;
    }
    __syncthreads();
    if (tid < 32) s_inv[tid] = 1.f / (s_red[tid] + s_red[32 + tid] + s_red[64 + tid] + s_red[96 + tid] + cs);
    __syncthreads();
    float inv4[4];
    #pragma unroll
    for (int r = 0; r < 4; r++) inv4[r] = s_inv[wr * 16 + quad * 4 + r];

    // ================= REPLAY: unpack cache, store scores, PV (no recompute) =================
    f32x4 oacc[2];
    oacc[0] = {0.f, 0.f, 0.f, 0.f};
    oacc[1] = {0.f, 0.f, 0.f, 0.f};
    float* scb = out + OUT_ELEMS + ((size_t)bh << 20)
               + (size_t)(n0 + wr * 16 + quad * 4) * 1024 + mq;

    #pragma unroll
    for (int t = 0; t < 16; t++) {
        const int m0 = t * 64;
        #pragma unroll
        for (int i = 0; i < 2; i++) {         // sVt: 128 dh x 8 short8
            int u = tid + i * 512;
            int dh = u >> 3, seg = u & 7;
            short8 d = *reinterpret_cast<const short8*>(wsVt + ((size_t)bh * 128 + dh) * 1024 + m0 + seg * 8);
            *reinterpret_cast<short8*>(&sVt[dh * 72 + seg * 8]) = d;
        }
        {
            unsigned pv0 = vreg[t][0], pv1 = vreg[t][1];
            unsigned short vb0 = (unsigned short)pv0, vb1 = (unsigned short)(pv0 >> 16);
            unsigned short vb2 = (unsigned short)pv1, vb3 = (unsigned short)(pv1 >> 16);
            unsigned short* pbase = &sP[(wr * 16 + quad * 4) * 72 + mq];
            pbase[0]   = vb0;
            pbase[72]  = vb1;
            pbase[144] = vb2;
            pbase[216] = vb3;
            scb[m0]        = __builtin_bit_cast(float, (unsigned)vb0 << 16) * inv4[0];
            scb[m0 + 1024] = __builtin_bit_cast(float, (unsigned)vb1 << 16) * inv4[1];
            scb[m0 + 2048] = __builtin_bit_cast(float, (unsigned)vb2 << 16) * inv4[2];
            scb[m0 + 3072] = __builtin_bit_cast(float, (unsigned)vb3 << 16) * inv4[3];
        }
        __syncthreads();   // sP + sVt ready
        #pragma unroll
        for (int ks2 = 0; ks2 < 2; ks2++) {
            short8 pfr = *reinterpret_cast<const short8*>(&sP[(wr * 16 + l15) * 72 + ks2 * 32 + quad * 8]);
            #pragma unroll
            for (int df = 0; df < 2; df++) {
                short8 vfr = *reinterpret_cast<const short8*>(&sVt[(wc * 32 + df * 16 + l15) * 72 + ks2 * 32 + quad * 8]);
                oacc[df] = __builtin_amdgcn_mfma_f32_16x16x32_bf16(pfr, vfr, oacc[df], 0, 0, 0);
            }
        }
        __syncthreads();   // PV reads done before next tile's writes
    }

    // ---- epilogue: O = inv[row] * acc (waves own disjoint (row,dh) -> no merge) ----
    {
        float* obase = out + ((size_t)bh * 1024 + n0 + wr * 16 + quad * 4) * 128 + wc * 32 + l15;
        #pragma unroll
        for (int df = 0; df < 2; df++)
            #pragma unroll
            for (int r = 0; r < 4; r++)
                obase[(size_t)r * 128 + df * 16] = oacc[df][r] * inv4[r];
    }
}

extern "C" void kernel_launch(void* const* d_in, const int* in_sizes, int n_in,
                              void* d_out, int out_size, void* d_ws, size_t ws_size,
                              hipStream_t stream) {
    const float* q   = (const float*)d_in[0];
    const float* k   = (const float*)d_in[1];
    const float* v   = (const float*)d_in[2];
    const float* c   = (const float*)d_in[3];
    const float* dq  = (const float*)d_in[4];
    const float* dk  = (const float*)d_in[5];
    const float* w_w = (const float*)d_in[6];
    const float* b_w = (const float*)d_in[7];
    const float* w_b = (const float*)d_in[8];
    const float* b_b = (const float*)d_in[9];
    float* out = (float*)d_out;
    char* ws = (char*)d_ws;
    unsigned short* wsK  = (unsigned short*)(ws + WS_K);
    unsigned short* wsVt = (unsigned short*)(ws + WS_VT);
    float* wsCs   = (float*)(ws + WS_CS);

    hipLaunchKernelGGL(prep_all, dim3(1056), dim3(256), 0, stream, k, v, c, wsK, wsVt, wsCs);
    hipLaunchKernelGGL(sam_main, dim3(1024), dim3(512), 0, stream,
                       q, dq, dk, w_w, b_w, w_b, b_b, wsK, wsVt, wsCs, out);
}